// Round 1
// baseline (4244.603 us; speedup 1.0000x reference)
//
#include <hip/hip_runtime.h>
#include <hip/hip_bf16.h>
#include <math.h>

// Gen3Dmol_Classify: B=8 N=256 D=768 H=8 HD=96 F=3072 K=128 L=8 V=32 E=1024 C=2
// fp32 reference-faithful implementation (round 0 baseline).

#define DEV_INLINE __device__ __forceinline__

DEV_INLINE float gelu_f(float v) {
  return 0.5f * v * (1.0f + erff(v * 0.70710678118654752f));
}

// ---------------------------------------------------------------------------
// Gaussian edge features + 2-layer MLP -> attn_bias[b][h][i][j]
// block = 256 threads, 32 positions per block. LDS ~58KB -> 2 blocks/CU.
// ---------------------------------------------------------------------------
__global__ __launch_bounds__(256) void k_gauss(
    const float* __restrict__ dist, const int* __restrict__ edge,
    const float* __restrict__ gmul, const float* __restrict__ gbias,
    const float* __restrict__ gmeans, const float* __restrict__ gstds,
    const float* __restrict__ gp1w, const float* __restrict__ gp1b,
    const float* __restrict__ gp2w, const float* __restrict__ gp2b,
    float* __restrict__ bias_out)
{
  __shared__ float gT[128][36];     // g transposed [k][pos], pad 36 (16B-aligned rows)
  __shared__ float tT[32][129];     // gelu(g@w1+b1) [pos][k2], pad 129 (conflict-free col reads)
  __shared__ float w1s[32][132];    // staged gp1w chunk [kk][k2]
  __shared__ float ys[32];
  __shared__ float mean_s[128], invstd_s[128], coef_s[128], b1s[128];
  __shared__ float w2s[128][8];
  __shared__ float b2s[8];

  const int t = threadIdx.x;
  const int pos0 = blockIdx.x * 32;

  if (t < 128) {
    float sd = fabsf(gstds[t]) + 1e-5f;
    invstd_s[t] = 1.0f / sd;
    coef_s[t] = 1.0f / (2.5066272f * sd);   // 1/(sqrt(2*3.14159)*std)
    b1s[t] = gp1b[t];
    mean_s[t] = gmeans[t];
  }
  for (int i = t; i < 1024; i += 256) w2s[i >> 3][i & 7] = gp2w[i];
  if (t < 8) b2s[t] = gp2b[t];
  if (t < 32) {
    int p = pos0 + t;
    int et = edge[p];
    ys[t] = gmul[et] * dist[p] + gbias[et];
  }
  __syncthreads();

  // phase 1: g[k][p] = exp(-0.5*((y-mean)/std)^2) / (A*std)
  {
    const int p = t & 31;
    const int kb = (t >> 5) << 4;    // 8 groups x 16 k
    const float y = ys[p];
    #pragma unroll
    for (int j = 0; j < 16; ++j) {
      int k = kb + j;
      float z = (y - mean_s[k]) * invstd_s[k];
      gT[k][p] = __expf(-0.5f * z * z) * coef_s[k];
    }
  }
  __syncthreads();

  // phase 2: t = gelu(g @ gp1w + b1)   (32 x 128)
  const int tm = (t >> 5) << 2;      // 4 positions
  const int tn = (t & 31) << 2;      // 4 k2
  float acc[4][4] = {};
  for (int c = 0; c < 4; ++c) {
    __syncthreads();                 // protect previous chunk reads
    #pragma unroll
    for (int l = 0; l < 4; ++l) {
      int idx = t + (l << 8);        // 0..1023
      int r = idx >> 5, c4 = (idx & 31) << 2;
      *(float4*)&w1s[r][c4] = *(const float4*)&gp1w[(c * 32 + r) * 128 + c4];
    }
    __syncthreads();
    #pragma unroll 8
    for (int kk = 0; kk < 32; ++kk) {
      int k = c * 32 + kk;
      float4 a4 = *(const float4*)&gT[k][tm];
      float4 b4 = *(const float4*)&w1s[kk][tn];
      float ar[4] = {a4.x, a4.y, a4.z, a4.w};
      float br[4] = {b4.x, b4.y, b4.z, b4.w};
      #pragma unroll
      for (int i = 0; i < 4; ++i)
        #pragma unroll
        for (int j = 0; j < 4; ++j)
          acc[i][j] = fmaf(ar[i], br[j], acc[i][j]);
    }
  }
  #pragma unroll
  for (int i = 0; i < 4; ++i)
    #pragma unroll
    for (int j = 0; j < 4; ++j)
      tT[tm + i][tn + j] = gelu_f(acc[i][j] + b1s[tn + j]);
  __syncthreads();

  // phase 3: pb[p][h] = t @ gp2w + b2 -> bias_out[b][h][i][j]
  {
    const int p = t & 31;
    const int h = t >> 5;
    float a = b2s[h];
    #pragma unroll 8
    for (int k2 = 0; k2 < 128; ++k2)
      a = fmaf(tT[p][k2], w2s[k2][h], a);
    int pos = pos0 + p;
    int b = pos >> 16, ij = pos & 65535;
    bias_out[(size_t)((b << 3) + h) * 65536 + ij] = a;
  }
}

// ---------------------------------------------------------------------------
// Embedding gather + LayerNorm (one block per row, D=768)
// ---------------------------------------------------------------------------
__global__ __launch_bounds__(256) void k_embed_ln(
    const float* __restrict__ emb, const int* __restrict__ tokens,
    const float* __restrict__ g, const float* __restrict__ bp,
    float* __restrict__ out)
{
  __shared__ float red[4], red2[4];
  const int t = threadIdx.x;
  const int row = blockIdx.x;
  const float* xr = emb + (size_t)tokens[row] * 768;
  float v0 = xr[t], v1 = xr[t + 256], v2 = xr[t + 512];
  float s = v0 + v1 + v2;
  #pragma unroll
  for (int o = 32; o; o >>= 1) s += __shfl_down(s, o);
  if ((t & 63) == 0) red[t >> 6] = s;
  __syncthreads();
  float mean = (red[0] + red[1] + red[2] + red[3]) * (1.0f / 768.0f);
  float d0 = v0 - mean, d1 = v1 - mean, d2 = v2 - mean;
  float q = d0 * d0 + d1 * d1 + d2 * d2;
  #pragma unroll
  for (int o = 32; o; o >>= 1) q += __shfl_down(q, o);
  if ((t & 63) == 0) red2[t >> 6] = q;
  __syncthreads();
  float rstd = rsqrtf((red2[0] + red2[1] + red2[2] + red2[3]) * (1.0f / 768.0f) + 1e-3f);
  float* outr = out + (size_t)row * 768;
  outr[t]       = d0 * rstd * g[t]       + bp[t];
  outr[t + 256] = d1 * rstd * g[t + 256] + bp[t + 256];
  outr[t + 512] = d2 * rstd * g[t + 512] + bp[t + 512];
}

__global__ __launch_bounds__(256) void k_ln(
    const float* __restrict__ in, const float* __restrict__ g,
    const float* __restrict__ bp, float* __restrict__ out)
{
  __shared__ float red[4], red2[4];
  const int t = threadIdx.x;
  const size_t base = (size_t)blockIdx.x * 768;
  const float* xr = in + base;
  float v0 = xr[t], v1 = xr[t + 256], v2 = xr[t + 512];
  float s = v0 + v1 + v2;
  #pragma unroll
  for (int o = 32; o; o >>= 1) s += __shfl_down(s, o);
  if ((t & 63) == 0) red[t >> 6] = s;
  __syncthreads();
  float mean = (red[0] + red[1] + red[2] + red[3]) * (1.0f / 768.0f);
  float d0 = v0 - mean, d1 = v1 - mean, d2 = v2 - mean;
  float q = d0 * d0 + d1 * d1 + d2 * d2;
  #pragma unroll
  for (int o = 32; o; o >>= 1) q += __shfl_down(q, o);
  if ((t & 63) == 0) red2[t >> 6] = q;
  __syncthreads();
  float rstd = rsqrtf((red2[0] + red2[1] + red2[2] + red2[3]) * (1.0f / 768.0f) + 1e-3f);
  float* outr = out + base;
  outr[t]       = d0 * rstd * g[t]       + bp[t];
  outr[t + 256] = d1 * rstd * g[t + 256] + bp[t + 256];
  outr[t + 512] = d2 * rstd * g[t + 512] + bp[t + 512];
}

// ---------------------------------------------------------------------------
// SGEMM: C[2048,N] = A[2048,K] @ Bw[K,N] + bias (+gelu | +residual)
// BM=BN=64, BK=16, 256 threads, 4x4 micro-tile, register prefetch.
// EPI: 0 = bias, 1 = bias+gelu, 2 = bias+residual
// ---------------------------------------------------------------------------
template<int EPI>
__global__ __launch_bounds__(256) void k_gemm64(
    const float* __restrict__ A, const float* __restrict__ Bw,
    const float* __restrict__ bias, const float* res,
    float* C, int N, int K)
{
  __shared__ float As[16][68];   // A transposed [k][m]
  __shared__ float Bs[16][68];   // B [k][n]
  const int t = threadIdx.x;
  const int row0 = blockIdx.x << 6;
  const int col0 = blockIdx.y << 6;
  const int tm = (t >> 4) << 2;
  const int tn = (t & 15) << 2;
  const int la_r = t >> 2;
  const int la_c = (t & 3) << 2;
  const int lb_r = t >> 4;
  const int lb_c = (t & 15) << 2;
  const float* Aptr = A + (size_t)(row0 + la_r) * K + la_c;
  const float* Bptr = Bw + (size_t)lb_r * N + col0 + lb_c;
  float acc[4][4] = {};
  float4 av = *(const float4*)Aptr;
  float4 bv = *(const float4*)Bptr;
  for (int k0 = 0; k0 < K; k0 += 16) {
    As[la_c + 0][la_r] = av.x;
    As[la_c + 1][la_r] = av.y;
    As[la_c + 2][la_r] = av.z;
    As[la_c + 3][la_r] = av.w;
    *(float4*)&Bs[lb_r][lb_c] = bv;
    __syncthreads();
    if (k0 + 16 < K) {            // prefetch next tiles into registers
      Aptr += 16;
      Bptr += (size_t)16 * N;
      av = *(const float4*)Aptr;
      bv = *(const float4*)Bptr;
    }
    #pragma unroll
    for (int k = 0; k < 16; ++k) {
      float4 a4 = *(const float4*)&As[k][tm];
      float4 b4 = *(const float4*)&Bs[k][tn];
      float ar[4] = {a4.x, a4.y, a4.z, a4.w};
      float br[4] = {b4.x, b4.y, b4.z, b4.w};
      #pragma unroll
      for (int i = 0; i < 4; ++i)
        #pragma unroll
        for (int j = 0; j < 4; ++j)
          acc[i][j] = fmaf(ar[i], br[j], acc[i][j]);
    }
    __syncthreads();
  }
  float4 bb = *(const float4*)&bias[col0 + tn];
  #pragma unroll
  for (int i = 0; i < 4; ++i) {
    size_t off = (size_t)(row0 + tm + i) * N + col0 + tn;
    float4 v;
    v.x = acc[i][0] + bb.x;
    v.y = acc[i][1] + bb.y;
    v.z = acc[i][2] + bb.z;
    v.w = acc[i][3] + bb.w;
    if (EPI == 1) { v.x = gelu_f(v.x); v.y = gelu_f(v.y); v.z = gelu_f(v.z); v.w = gelu_f(v.w); }
    if (EPI == 2) {
      float4 rv = *(const float4*)&res[off];
      v.x += rv.x; v.y += rv.y; v.z += rv.z; v.w += rv.w;
    }
    *(float4*)&C[off] = v;
  }
}

// ---------------------------------------------------------------------------
// Scores: S[bh][i][j] = scale * dot(P[b,i,h,:], P[b,j,h,:]) + attn_bias
// 64x64 tile, K=96 fully LDS-resident. grid (4,4,64).
// ---------------------------------------------------------------------------
__global__ __launch_bounds__(256) void k_scores(
    const float* __restrict__ P, const float* __restrict__ bias,
    float* __restrict__ S)
{
  __shared__ float Qs[96][68];
  __shared__ float Ks[96][68];
  const int t = threadIdx.x;
  const int i0 = blockIdx.x << 6;
  const int j0 = blockIdx.y << 6;
  const int bh = blockIdx.z;
  const int b = bh >> 3, h = bh & 7;
  const float* Pq = P + ((size_t)b * 256 + i0) * 768 + h * 96;
  const float* Pk = P + ((size_t)b * 256 + j0) * 768 + h * 96;
  #pragma unroll
  for (int l = 0; l < 6; ++l) {
    int idx = t + (l << 8);          // 0..1535
    int r = idx / 24;
    int c = (idx % 24) << 2;
    float4 q = *(const float4*)&Pq[(size_t)r * 768 + c];
    Qs[c][r] = q.x; Qs[c + 1][r] = q.y; Qs[c + 2][r] = q.z; Qs[c + 3][r] = q.w;
    float4 kv = *(const float4*)&Pk[(size_t)r * 768 + c];
    Ks[c][r] = kv.x; Ks[c + 1][r] = kv.y; Ks[c + 2][r] = kv.z; Ks[c + 3][r] = kv.w;
  }
  __syncthreads();
  const int tm = (t >> 4) << 2;
  const int tn = (t & 15) << 2;
  float acc[4][4] = {};
  #pragma unroll 8
  for (int d = 0; d < 96; ++d) {
    float4 a4 = *(const float4*)&Qs[d][tm];
    float4 b4 = *(const float4*)&Ks[d][tn];
    float ar[4] = {a4.x, a4.y, a4.z, a4.w};
    float br[4] = {b4.x, b4.y, b4.z, b4.w};
    #pragma unroll
    for (int i = 0; i < 4; ++i)
      #pragma unroll
      for (int j = 0; j < 4; ++j)
        acc[i][j] = fmaf(ar[i], br[j], acc[i][j]);
  }
  const float scale = 0.102062072615966f;  // 1/sqrt(96)
  #pragma unroll
  for (int i = 0; i < 4; ++i) {
    size_t off = ((size_t)bh * 256 + i0 + tm + i) * 256 + j0 + tn;
    float4 bb = *(const float4*)&bias[off];
    float4 v;
    v.x = fmaf(acc[i][0], scale, bb.x);
    v.y = fmaf(acc[i][1], scale, bb.y);
    v.z = fmaf(acc[i][2], scale, bb.z);
    v.w = fmaf(acc[i][3], scale, bb.w);
    *(float4*)&S[off] = v;
  }
}

// ---------------------------------------------------------------------------
// Row softmax over 256 elements (one block per row).
// ---------------------------------------------------------------------------
__global__ __launch_bounds__(256) void k_softmax(float* __restrict__ S)
{
  __shared__ float red[8];
  const int t = threadIdx.x;
  float* p = S + (size_t)blockIdx.x * 256;
  float v = p[t];
  float m = v;
  #pragma unroll
  for (int o = 32; o; o >>= 1) m = fmaxf(m, __shfl_down(m, o));
  if ((t & 63) == 0) red[t >> 6] = m;
  __syncthreads();
  m = fmaxf(fmaxf(red[0], red[1]), fmaxf(red[2], red[3]));
  float e = __expf(v - m);
  float s = e;
  #pragma unroll
  for (int o = 32; o; o >>= 1) s += __shfl_down(s, o);
  if ((t & 63) == 0) red[4 + (t >> 6)] = s;
  __syncthreads();
  s = red[4] + red[5] + red[6] + red[7];
  p[t] = e / s;
}

// ---------------------------------------------------------------------------
// O = softmax(S) @ V, written directly into (B,N,D) layout.
// per block: 64 rows x 96 cols, K=256 in chunks of 32. grid (4,64).
// ---------------------------------------------------------------------------
__global__ __launch_bounds__(256) void k_attn_o(
    const float* __restrict__ S, const float* __restrict__ P,
    float* __restrict__ O)
{
  __shared__ float Ps[32][68];    // scores transposed [k][m]
  __shared__ float Vs[32][100];   // V [k][d]
  const int t = threadIdx.x;
  const int m0 = blockIdx.x << 6;
  const int bh = blockIdx.y;
  const int b = bh >> 3, h = bh & 7;
  const float* Srow = S + ((size_t)bh * 256 + m0) * 256;
  const float* Vbase = P + (size_t)b * 256 * 768 + h * 96;
  const int tm = (t >> 4) << 2;
  const int tn = (t & 15) * 6;
  float acc[4][6] = {};
  for (int k0 = 0; k0 < 256; k0 += 32) {
    __syncthreads();
    #pragma unroll
    for (int l = 0; l < 2; ++l) {
      int idx = t + (l << 8);       // 0..511
      int r = idx >> 3, c = (idx & 7) << 2;
      float4 s4 = *(const float4*)&Srow[(size_t)r * 256 + k0 + c];
      Ps[c][r] = s4.x; Ps[c + 1][r] = s4.y; Ps[c + 2][r] = s4.z; Ps[c + 3][r] = s4.w;
    }
    #pragma unroll
    for (int l = 0; l < 3; ++l) {
      int idx = t + (l << 8);       // 0..767
      int r = idx / 24, c = (idx % 24) << 2;
      *(float4*)&Vs[r][c] = *(const float4*)&Vbase[(size_t)(k0 + r) * 768 + c];
    }
    __syncthreads();
    #pragma unroll 8
    for (int k = 0; k < 32; ++k) {
      float4 a4 = *(const float4*)&Ps[k][tm];
      float ar[4] = {a4.x, a4.y, a4.z, a4.w};
      float br[6];
      float2 b0 = *(const float2*)&Vs[k][tn];
      float2 b1v = *(const float2*)&Vs[k][tn + 2];
      float2 b2v = *(const float2*)&Vs[k][tn + 4];
      br[0] = b0.x; br[1] = b0.y; br[2] = b1v.x; br[3] = b1v.y; br[4] = b2v.x; br[5] = b2v.y;
      #pragma unroll
      for (int i = 0; i < 4; ++i)
        #pragma unroll
        for (int j = 0; j < 6; ++j)
          acc[i][j] = fmaf(ar[i], br[j], acc[i][j]);
    }
  }
  float* Orow = O + ((size_t)b * 256 + m0) * 768 + h * 96;
  #pragma unroll
  for (int i = 0; i < 4; ++i) {
    float2 w0 = {acc[i][0], acc[i][1]};
    float2 w1 = {acc[i][2], acc[i][3]};
    float2 w2 = {acc[i][4], acc[i][5]};
    *(float2*)&Orow[(size_t)(tm + i) * 768 + tn]     = w0;
    *(float2*)&Orow[(size_t)(tm + i) * 768 + tn + 2] = w1;
    *(float2*)&Orow[(size_t)(tm + i) * 768 + tn + 4] = w2;
  }
}

// ---------------------------------------------------------------------------
// Final LN (row 0 of each batch) + classifier head -> out (8,2)
// ---------------------------------------------------------------------------
__global__ __launch_bounds__(256) void k_cls(
    const float* __restrict__ x, const float* __restrict__ fg,
    const float* __restrict__ fb, const float* __restrict__ w1,
    const float* __restrict__ b1, const float* __restrict__ w2,
    const float* __restrict__ b2, float* __restrict__ out)
{
  __shared__ float ln[768];
  __shared__ float t1[768];
  __shared__ float red[8];
  __shared__ float r2[8];
  const int t = threadIdx.x;
  const int b = blockIdx.x;
  const float* xr = x + (size_t)b * 256 * 768;   // row (b, 0)
  float v0 = xr[t], v1 = xr[t + 256], v2 = xr[t + 512];
  float s = v0 + v1 + v2;
  #pragma unroll
  for (int o = 32; o; o >>= 1) s += __shfl_down(s, o);
  if ((t & 63) == 0) red[t >> 6] = s;
  __syncthreads();
  float mean = (red[0] + red[1] + red[2] + red[3]) * (1.0f / 768.0f);
  float d0 = v0 - mean, d1 = v1 - mean, d2 = v2 - mean;
  float q = d0 * d0 + d1 * d1 + d2 * d2;
  #pragma unroll
  for (int o = 32; o; o >>= 1) q += __shfl_down(q, o);
  if ((t & 63) == 0) red[4 + (t >> 6)] = q;
  __syncthreads();
  float rstd = rsqrtf((red[4] + red[5] + red[6] + red[7]) * (1.0f / 768.0f) + 1e-3f);
  ln[t]       = d0 * rstd * fg[t]       + fb[t];
  ln[t + 256] = d1 * rstd * fg[t + 256] + fb[t + 256];
  ln[t + 512] = d2 * rstd * fg[t + 512] + fb[t + 512];
  __syncthreads();
  float a0 = b1[t], a1 = b1[t + 256], a2 = b1[t + 512];
  for (int d = 0; d < 768; ++d) {
    float lv = ln[d];
    a0 = fmaf(lv, w1[d * 768 + t], a0);
    a1 = fmaf(lv, w1[d * 768 + t + 256], a1);
    a2 = fmaf(lv, w1[d * 768 + t + 512], a2);
  }
  t1[t]       = gelu_f(a0);
  t1[t + 256] = gelu_f(a1);
  t1[t + 512] = gelu_f(a2);
  __syncthreads();
  float p0 = 0.f, p1 = 0.f;
  #pragma unroll
  for (int oo = 0; oo < 3; ++oo) {
    int d = t + oo * 256;
    p0 = fmaf(t1[d], w2[d * 2], p0);
    p1 = fmaf(t1[d], w2[d * 2 + 1], p1);
  }
  #pragma unroll
  for (int o = 32; o; o >>= 1) {
    p0 += __shfl_down(p0, o);
    p1 += __shfl_down(p1, o);
  }
  if ((t & 63) == 0) { r2[t >> 6] = p0; r2[4 + (t >> 6)] = p1; }
  __syncthreads();
  if (t == 0) {
    out[b * 2]     = r2[0] + r2[1] + r2[2] + r2[3] + b2[0];
    out[b * 2 + 1] = r2[4] + r2[5] + r2[6] + r2[7] + b2[1];
  }
}

// ---------------------------------------------------------------------------
extern "C" void kernel_launch(void* const* d_in, const int* in_sizes, int n_in,
                              void* d_out, int out_size, void* d_ws, size_t ws_size,
                              hipStream_t stream)
{
  const float* dist    = (const float*)d_in[0];
  const float* tok_emb = (const float*)d_in[1];
  const float* gmeans  = (const float*)d_in[2];
  const float* gstds   = (const float*)d_in[3];
  const float* gmul    = (const float*)d_in[4];
  const float* gbias   = (const float*)d_in[5];
  const float* gp1w    = (const float*)d_in[6];
  const float* gp1b    = (const float*)d_in[7];
  const float* gp2w    = (const float*)d_in[8];
  const float* gp2b    = (const float*)d_in[9];
  const float* embg    = (const float*)d_in[10];
  const float* embb    = (const float*)d_in[11];
  const float* Wq      = (const float*)d_in[12];
  const float* bq      = (const float*)d_in[13];
  const float* Wo      = (const float*)d_in[14];
  const float* bo      = (const float*)d_in[15];
  const float* ln1g    = (const float*)d_in[16];
  const float* ln1b    = (const float*)d_in[17];
  const float* W1      = (const float*)d_in[18];
  const float* b1      = (const float*)d_in[19];
  const float* W2      = (const float*)d_in[20];
  const float* b2      = (const float*)d_in[21];
  const float* ln2g    = (const float*)d_in[22];
  const float* ln2b    = (const float*)d_in[23];
  const float* fing    = (const float*)d_in[24];
  const float* finb    = (const float*)d_in[25];
  const float* cw1     = (const float*)d_in[26];
  const float* cb1     = (const float*)d_in[27];
  const float* cw2     = (const float*)d_in[28];
  const float* cb2     = (const float*)d_in[29];
  const int*   tokens  = (const int*)d_in[30];
  const int*   edge    = (const int*)d_in[31];

  float* ws   = (float*)d_ws;
  float* bias = ws;                   // 4,194,304 f  (B*H*N*N)
  float* sc   = bias + 4194304;       // 6,291,456 f  (scores 4.19M / FFN 6.29M, aliased)
  float* x    = sc + 6291456;         // 1,572,864 f  (B*N*D)
  float* h    = x + 1572864;          // 1,572,864 f
  float* P    = h + 1572864;          // 1,572,864 f  (shared q/k/v projection)
  float* o    = P + 1572864;          // 1,572,864 f
  // total = 16,777,216 floats = 64 MiB

  k_gauss<<<16384, 256, 0, stream>>>(dist, edge, gmul, gbias, gmeans, gstds,
                                     gp1w, gp1b, gp2w, gp2b, bias);
  k_embed_ln<<<2048, 256, 0, stream>>>(tok_emb, tokens, embg, embb, x);

  for (int l = 0; l < 8; ++l) {
    k_ln<<<2048, 256, 0, stream>>>(x, ln1g + l * 768, ln1b + l * 768, h);
    k_gemm64<0><<<dim3(32, 12), 256, 0, stream>>>(
        h, Wq + (size_t)l * 768 * 768, bq + l * 768, nullptr, P, 768, 768);
    k_scores<<<dim3(4, 4, 64), 256, 0, stream>>>(P, bias, sc);
    k_softmax<<<16384, 256, 0, stream>>>(sc);
    k_attn_o<<<dim3(4, 64), 256, 0, stream>>>(sc, P, o);
    k_gemm64<2><<<dim3(32, 12), 256, 0, stream>>>(
        o, Wo + (size_t)l * 768 * 768, bo + l * 768, x, x, 768, 768);
    k_ln<<<2048, 256, 0, stream>>>(x, ln2g + l * 768, ln2b + l * 768, h);
    k_gemm64<1><<<dim3(32, 48), 256, 0, stream>>>(
        h, W1 + (size_t)l * 768 * 3072, b1 + l * 3072, nullptr, sc, 3072, 768);
    k_gemm64<2><<<dim3(32, 12), 256, 0, stream>>>(
        sc, W2 + (size_t)l * 3072 * 768, b2 + l * 768, x, x, 768, 3072);
  }
  k_cls<<<8, 256, 0, stream>>>(x, fing, finb, cw1, cb1, cw2, cb2, (float*)d_out);
}

// Round 2
// 1135.108 us; speedup vs baseline: 3.7394x; 3.7394x over previous
//
#include <hip/hip_runtime.h>
#include <hip/hip_bf16.h>
#include <math.h>

// Gen3Dmol_Classify: B=8 N=256 D=768 H=8 HD=96 F=3072 K=128 L=8 V=32 E=1024 C=2
// Round 1: bf16 MFMA for all GEMM-shaped work, fp32 residual/LN/softmax.

#define DEV_INLINE __device__ __forceinline__

typedef __attribute__((ext_vector_type(8))) short short8v;
typedef __attribute__((ext_vector_type(4))) short short4v;
typedef __attribute__((ext_vector_type(4))) float f32x4;

DEV_INLINE unsigned short f2bf(float f) {
  unsigned u = __float_as_uint(f);
  return (unsigned short)((u + 0x7fffu + ((u >> 16) & 1u)) >> 16);
}
DEV_INLINE float gelu_f(float v) {
  return 0.5f * v * (1.0f + erff(v * 0.70710678118654752f));
}
DEV_INLINE f32x4 zero4() { f32x4 z; z[0]=0.f; z[1]=0.f; z[2]=0.f; z[3]=0.f; return z; }

// ---------------------------------------------------------------------------
// Weight cast + transpose: W[K][N] fp32 -> Wt[N][K] bf16 (per blockIdx.z layer)
// ---------------------------------------------------------------------------
__global__ __launch_bounds__(256) void k_cast_t(
    const float* __restrict__ W, unsigned short* __restrict__ Wt, int K, int N)
{
  __shared__ float s[64][68];
  const int tid = threadIdx.x;
  const size_t lay = (size_t)blockIdx.z * K * N;
  const int k0 = blockIdx.x * 64, n0 = blockIdx.y * 64;
  const int r = tid >> 4, c4 = (tid & 15) << 2;
  #pragma unroll
  for (int i = 0; i < 4; ++i)
    *(float4*)&s[r + i * 16][c4] =
        *(const float4*)(W + lay + (size_t)(k0 + r + i * 16) * N + n0 + c4);
  __syncthreads();
  const int n = tid & 63, kc = (tid >> 6) << 4;
  short8v v0, v1;
  #pragma unroll
  for (int j = 0; j < 8; ++j) v0[j] = (short)f2bf(s[kc + j][n]);
  #pragma unroll
  for (int j = 0; j < 8; ++j) v1[j] = (short)f2bf(s[kc + 8 + j][n]);
  unsigned short* dst = Wt + lay + (size_t)(n0 + n) * K + k0 + kc;
  *(short8v*)dst = v0;
  *(short8v*)(dst + 8) = v1;
}

// ---------------------------------------------------------------------------
// MFMA GEMM: C[2048][N] = A[2048][K](bf16) @ Bt[N][K](bf16)^T + bias
// BM=128, BK=64, BN in {64,128}. 256 thr = 4 waves (2x2), wave tile 64 x BN/2.
// EPI: 0 = bias -> bf16 out; 1 = bias+gelu -> bf16; 2 = bias+res -> fp32.
// LDS: linear rows of 128B with XOR swizzle byte^=((row&7)<<4).
// ---------------------------------------------------------------------------
template<int BN, int EPI>
__global__ __launch_bounds__(256) void k_gemm(
    const unsigned short* __restrict__ A, const unsigned short* __restrict__ Bt,
    const float* __restrict__ bias, const float* __restrict__ res,
    void* __restrict__ Cout, int N, int K)
{
  constexpr int NB = BN / 32;   // stage chunks for B / b-frags per kk
  __shared__ __align__(16) unsigned short As[128 * 64];
  __shared__ __align__(16) unsigned short Bs[BN * 64];
  const int tid = threadIdx.x;
  const int l = tid & 63;
  const int w = tid >> 6, wr = w >> 1, wc = w & 1;
  const int row0 = blockIdx.x * 128, col0 = blockIdx.y * BN;
  const int NT = K >> 6;

  // staging geometry: chunk i covers rows i*32 + (tid>>3), 16B at col (tid&7)*16
  const int rA = tid >> 3;
  const int cs = (((tid & 7) * 16) ^ ((rA & 7) << 4)) >> 1;  // swizzled elem off
  const unsigned short* pa = A + (size_t)(row0 + rA) * K + (tid & 7) * 8;
  const unsigned short* pb = Bt + (size_t)(col0 + rA) * K + (tid & 7) * 8;

  short8v ra[4], rb[NB];
  #pragma unroll
  for (int i = 0; i < 4; ++i) ra[i] = *(const short8v*)(pa + (size_t)i * 32 * K);
  #pragma unroll
  for (int i = 0; i < NB; ++i) rb[i] = *(const short8v*)(pb + (size_t)i * 32 * K);

  f32x4 acc[4][NB];
  #pragma unroll
  for (int mi = 0; mi < 4; ++mi)
    #pragma unroll
    for (int ni = 0; ni < NB; ++ni) acc[mi][ni] = zero4();

  for (int kt = 0; kt < NT; ++kt) {
    #pragma unroll
    for (int i = 0; i < 4; ++i) *(short8v*)&As[(rA + i * 32) * 64 + cs] = ra[i];
    #pragma unroll
    for (int i = 0; i < NB; ++i) *(short8v*)&Bs[(rA + i * 32) * 64 + cs] = rb[i];
    __syncthreads();
    if (kt + 1 < NT) {
      const unsigned short* qa = pa + (size_t)(kt + 1) * 64;
      const unsigned short* qb = pb + (size_t)(kt + 1) * 64;
      #pragma unroll
      for (int i = 0; i < 4; ++i) ra[i] = *(const short8v*)(qa + (size_t)i * 32 * K);
      #pragma unroll
      for (int i = 0; i < NB; ++i) rb[i] = *(const short8v*)(qb + (size_t)i * 32 * K);
    }
    #pragma unroll
    for (int kk = 0; kk < 2; ++kk) {
      short8v af[4], bf_[NB];
      #pragma unroll
      for (int mi = 0; mi < 4; ++mi) {
        int rw = wr * 64 + mi * 16 + (l & 15);
        int kb = (kk * 64 + ((l >> 4) << 4)) ^ ((rw & 7) << 4);
        af[mi] = *(const short8v*)&As[rw * 64 + (kb >> 1)];
      }
      #pragma unroll
      for (int ni = 0; ni < NB; ++ni) {
        int rw = wc * (BN / 2) + ni * 16 + (l & 15);
        int kb = (kk * 64 + ((l >> 4) << 4)) ^ ((rw & 7) << 4);
        bf_[ni] = *(const short8v*)&Bs[rw * 64 + (kb >> 1)];
      }
      #pragma unroll
      for (int mi = 0; mi < 4; ++mi)
        #pragma unroll
        for (int ni = 0; ni < NB; ++ni)
          acc[mi][ni] = __builtin_amdgcn_mfma_f32_16x16x32_bf16(
              af[mi], bf_[ni], acc[mi][ni], 0, 0, 0);
    }
    __syncthreads();
  }

  // epilogue: C/D layout col=lane&15, row=(lane>>4)*4+reg
  const int cl = l & 15, rg = (l >> 4) << 2;
  float bv[NB];
  #pragma unroll
  for (int ni = 0; ni < NB; ++ni)
    bv[ni] = bias[col0 + wc * (BN / 2) + ni * 16 + cl];
  #pragma unroll
  for (int mi = 0; mi < 4; ++mi) {
    #pragma unroll
    for (int r = 0; r < 4; ++r) {
      size_t rowg = row0 + wr * 64 + mi * 16 + rg + r;
      #pragma unroll
      for (int ni = 0; ni < NB; ++ni) {
        size_t off = rowg * N + col0 + wc * (BN / 2) + ni * 16 + cl;
        float v = acc[mi][ni][r] + bv[ni];
        if (EPI == 0) ((unsigned short*)Cout)[off] = f2bf(v);
        if (EPI == 1) ((unsigned short*)Cout)[off] = f2bf(gelu_f(v));
        if (EPI == 2) ((float*)Cout)[off] = v + res[off];
      }
    }
  }
}

// ---------------------------------------------------------------------------
// Gaussian edge features + MLP via MFMA. 64 positions/block, 4 waves x 16 rows.
// ---------------------------------------------------------------------------
__global__ __launch_bounds__(256) void k_gauss(
    const float* __restrict__ dist, const int* __restrict__ edge,
    const float* __restrict__ gmul, const float* __restrict__ gbias,
    const float* __restrict__ gmeans, const float* __restrict__ gstds,
    const unsigned short* __restrict__ gp1wt, const float* __restrict__ gp1b,
    const float* __restrict__ gp2w, const float* __restrict__ gp2b,
    float* __restrict__ bias_out)
{
  __shared__ float ys[64];
  __shared__ float mean_s[128], inv_s[128], coef_s[128], b1s[128];
  __shared__ float b2s[8];
  __shared__ __align__(16) unsigned short t1[64 * 128];  // swizzled rows of 256B
  __shared__ __align__(16) unsigned short w2t[16 * 136];
  const int tid = threadIdx.x, l = tid & 63, w = tid >> 6;
  const int pos0 = blockIdx.x * 64;

  if (tid < 128) {
    float sd = fabsf(gstds[tid]) + 1e-5f;
    inv_s[tid] = 1.0f / sd;
    coef_s[tid] = 0.39894250f / sd;   // 1/sqrt(2*3.14159)/sd
    mean_s[tid] = gmeans[tid];
    b1s[tid] = gp1b[tid];
  }
  if (tid < 8) b2s[tid] = gp2b[tid];
  for (int i = tid; i < 2048; i += 256) {
    int hh = i & 15, k = i >> 4;
    w2t[hh * 136 + k] = (hh < 8) ? f2bf(gp2w[k * 8 + hh]) : (unsigned short)0;
  }
  if (tid < 64) {
    int p = pos0 + tid;
    int et = edge[p];
    ys[tid] = gmul[et] * dist[p] + gbias[et];
  }
  __syncthreads();

  // phase A: gaussians straight into A-fragments (row=lane&15, k=(lane>>4)*8+j)
  short8v ga[4];
  const float y = ys[w * 16 + (l & 15)];
  #pragma unroll
  for (int ks = 0; ks < 4; ++ks) {
    #pragma unroll
    for (int j = 0; j < 8; ++j) {
      int k = ks * 32 + ((l >> 4) << 3) + j;
      float z = (y - mean_s[k]) * inv_s[k];
      ga[ks][j] = (short)f2bf(__expf(-0.5f * z * z) * coef_s[k]);
    }
  }
  // phase B: t = g @ gp1w  (B-frags straight from L2-hot gp1wt)
  f32x4 acc[8];
  #pragma unroll
  for (int n = 0; n < 8; ++n) {
    acc[n] = zero4();
    const unsigned short* bp = gp1wt + (size_t)(n * 16 + (l & 15)) * 128 + ((l >> 4) << 3);
    #pragma unroll
    for (int ks = 0; ks < 4; ++ks)
      acc[n] = __builtin_amdgcn_mfma_f32_16x16x32_bf16(
          ga[ks], *(const short8v*)(bp + ks * 32), acc[n], 0, 0, 0);
  }
  // gelu -> t1 LDS (swizzled)
  {
    int rbase = w * 16 + ((l >> 4) << 2);
    #pragma unroll
    for (int n = 0; n < 8; ++n) {
      int col2 = (n * 16 + (l & 15)) * 2;
      float bb = b1s[n * 16 + (l & 15)];
      #pragma unroll
      for (int r = 0; r < 4; ++r) {
        int row = rbase + r;
        int byte = row * 256 + (col2 ^ ((row & 7) << 4));
        t1[byte >> 1] = f2bf(gelu_f(acc[n][r] + bb));
      }
    }
  }
  __syncthreads();
  // phase C: pb = t1 @ gp2w (N padded 8->16)
  f32x4 o4 = zero4();
  {
    int row = w * 16 + (l & 15);
    int swz = (row & 7) << 4;
    #pragma unroll
    for (int ks = 0; ks < 4; ++ks) {
      short8v af = *(const short8v*)&t1[(row * 256 + ((ks * 64 + ((l >> 4) << 4)) ^ swz)) >> 1];
      short8v bf_ = *(const short8v*)&w2t[(l & 15) * 136 + ks * 32 + ((l >> 4) << 3)];
      o4 = __builtin_amdgcn_mfma_f32_16x16x32_bf16(af, bf_, o4, 0, 0, 0);
    }
  }
  int hh = l & 15;
  if (hh < 8) {
    int b = pos0 >> 16;
    int ij = (pos0 & 65535) + w * 16 + ((l >> 4) << 2);
    float4 vv;
    vv.x = o4[0] + b2s[hh]; vv.y = o4[1] + b2s[hh];
    vv.z = o4[2] + b2s[hh]; vv.w = o4[3] + b2s[hh];
    *(float4*)(bias_out + ((size_t)((b << 3) + hh) << 16) + ij) = vv;
  }
}

// ---------------------------------------------------------------------------
// Embedding gather + LayerNorm -> fp32 x
// ---------------------------------------------------------------------------
__global__ __launch_bounds__(256) void k_embed_ln(
    const float* __restrict__ emb, const int* __restrict__ tokens,
    const float* __restrict__ g, const float* __restrict__ bp,
    float* __restrict__ out)
{
  __shared__ float red[4], red2[4];
  const int t = threadIdx.x;
  const int row = blockIdx.x;
  const float* xr = emb + (size_t)tokens[row] * 768;
  float v0 = xr[t], v1 = xr[t + 256], v2 = xr[t + 512];
  float s = v0 + v1 + v2;
  #pragma unroll
  for (int o = 32; o; o >>= 1) s += __shfl_down(s, o);
  if ((t & 63) == 0) red[t >> 6] = s;
  __syncthreads();
  float mean = (red[0] + red[1] + red[2] + red[3]) * (1.0f / 768.0f);
  float d0 = v0 - mean, d1 = v1 - mean, d2 = v2 - mean;
  float q = d0 * d0 + d1 * d1 + d2 * d2;
  #pragma unroll
  for (int o = 32; o; o >>= 1) q += __shfl_down(q, o);
  if ((t & 63) == 0) red2[t >> 6] = q;
  __syncthreads();
  float rstd = rsqrtf((red2[0] + red2[1] + red2[2] + red2[3]) * (1.0f / 768.0f) + 1e-3f);
  float* outr = out + (size_t)row * 768;
  outr[t]       = d0 * rstd * g[t]       + bp[t];
  outr[t + 256] = d1 * rstd * g[t + 256] + bp[t + 256];
  outr[t + 512] = d2 * rstd * g[t + 512] + bp[t + 512];
}

// LayerNorm fp32 -> bf16 h (GEMM A operand)
__global__ __launch_bounds__(256) void k_ln_bf(
    const float* __restrict__ in, const float* __restrict__ g,
    const float* __restrict__ bp, unsigned short* __restrict__ out)
{
  __shared__ float red[4], red2[4];
  const int t = threadIdx.x;
  const size_t base = (size_t)blockIdx.x * 768;
  const float* xr = in + base;
  float v0 = xr[t], v1 = xr[t + 256], v2 = xr[t + 512];
  float s = v0 + v1 + v2;
  #pragma unroll
  for (int o = 32; o; o >>= 1) s += __shfl_down(s, o);
  if ((t & 63) == 0) red[t >> 6] = s;
  __syncthreads();
  float mean = (red[0] + red[1] + red[2] + red[3]) * (1.0f / 768.0f);
  float d0 = v0 - mean, d1 = v1 - mean, d2 = v2 - mean;
  float q = d0 * d0 + d1 * d1 + d2 * d2;
  #pragma unroll
  for (int o = 32; o; o >>= 1) q += __shfl_down(q, o);
  if ((t & 63) == 0) red2[t >> 6] = q;
  __syncthreads();
  float rstd = rsqrtf((red2[0] + red2[1] + red2[2] + red2[3]) * (1.0f / 768.0f) + 1e-3f);
  unsigned short* outr = out + base;
  outr[t]       = f2bf(d0 * rstd * g[t]       + bp[t]);
  outr[t + 256] = f2bf(d1 * rstd * g[t + 256] + bp[t + 256]);
  outr[t + 512] = f2bf(d2 * rstd * g[t + 512] + bp[t + 512]);
}

// ---------------------------------------------------------------------------
// V transpose: P[b][tok][h*96+d] -> Vt[bh][d][tok]  (bf16)
// ---------------------------------------------------------------------------
__global__ __launch_bounds__(256) void k_transV(
    const unsigned short* __restrict__ P, unsigned short* __restrict__ Vt)
{
  __shared__ unsigned short s[64 * 100];
  const int tid = threadIdx.x;
  const int i0 = blockIdx.x * 64, bh = blockIdx.y, b = bh >> 3, h = bh & 7;
  const unsigned short* Pb = P + ((size_t)b * 256 + i0) * 768 + h * 96;
  #pragma unroll
  for (int i = 0; i < 6; ++i) {
    int o = (tid + i * 256) * 8;          // byte offset in logical [64][192B]
    int row = o / 192, c = o - row * 192;
    *(short4v*)&s[row * 100 + (c >> 1)] =
        *(const short4v*)(Pb + (size_t)row * 768 + (c >> 1));
  }
  __syncthreads();
  #pragma unroll
  for (int i = 0; i < 3; ++i) {
    int u = tid + i * 256;               // u < 768: d = u>>3, tok chunk (u&7)*8
    int d = u >> 3, tk = (u & 7) << 3;
    short8v v;
    #pragma unroll
    for (int j = 0; j < 8; ++j) v[j] = (short)s[(tk + j) * 100 + d];
    *(short8v*)(Vt + ((size_t)bh * 96 + d) * 256 + i0 + tk) = v;
  }
}

// ---------------------------------------------------------------------------
// Fused scores + softmax: probs = softmax(scale*P_q.P_k^T + bias) as bf16.
// Block: 64 q-rows x one bh. K-tile (256x96) LDS-staged, swizzle (row&3)<<4.
// ---------------------------------------------------------------------------
__global__ __launch_bounds__(256) void k_scores_sm(
    const unsigned short* __restrict__ P, const float* __restrict__ bias,
    unsigned short* __restrict__ probs)
{
  __shared__ __align__(16) unsigned short Ks[256 * 96];
  const int tid = threadIdx.x, l = tid & 63, w = tid >> 6;
  const int i0 = blockIdx.x * 64, bh = blockIdx.y, b = bh >> 3, h = bh & 7;
  const unsigned short* Pb = P + (size_t)b * 256 * 768 + h * 96;
  #pragma unroll
  for (int i = 0; i < 12; ++i) {
    int o = i * 4096 + tid * 16;
    int row = o / 192, c = o - row * 192;
    short8v v = *(const short8v*)(Pb + (size_t)row * 768 + (c >> 1));
    *(short8v*)&Ks[row * 96 + ((c ^ ((row & 3) << 4)) >> 1)] = v;
  }
  short8v aq[3];
  const int rq = i0 + w * 16 + (l & 15);
  #pragma unroll
  for (int ks = 0; ks < 3; ++ks)
    aq[ks] = *(const short8v*)(Pb + (size_t)rq * 768 + ks * 32 + ((l >> 4) << 3));
  __syncthreads();

  f32x4 acc[16];
  #pragma unroll
  for (int n = 0; n < 16; ++n) {
    acc[n] = zero4();
    int rk = n * 16 + (l & 15);
    int swz = (rk & 3) << 4;
    #pragma unroll
    for (int ks = 0; ks < 3; ++ks) {
      short8v bq = *(const short8v*)&Ks[rk * 96 + (((ks * 64 + ((l >> 4) << 4)) ^ swz) >> 1)];
      acc[n] = __builtin_amdgcn_mfma_f32_16x16x32_bf16(aq[ks], bq, acc[n], 0, 0, 0);
    }
  }
  // fused softmax: lane holds rows (l>>4)*4+r, cols (l&15)+16n
  const float scale = 0.10206207261596577f;  // 1/sqrt(96)
  const int cl = l & 15;
  const size_t base = ((size_t)bh * 256 + i0 + w * 16 + ((l >> 4) << 2)) * 256 + cl;
  #pragma unroll
  for (int r = 0; r < 4; ++r) {
    size_t rb = base + (size_t)r * 256;
    float m = -1e30f;
    #pragma unroll
    for (int n = 0; n < 16; ++n) {
      float v = acc[n][r] * scale + bias[rb + n * 16];
      acc[n][r] = v;
      m = fmaxf(m, v);
    }
    m = fmaxf(m, __shfl_xor(m, 1)); m = fmaxf(m, __shfl_xor(m, 2));
    m = fmaxf(m, __shfl_xor(m, 4)); m = fmaxf(m, __shfl_xor(m, 8));
    float sum = 0.f;
    #pragma unroll
    for (int n = 0; n < 16; ++n) {
      float e = __expf(acc[n][r] - m);
      acc[n][r] = e;
      sum += e;
    }
    sum += __shfl_xor(sum, 1); sum += __shfl_xor(sum, 2);
    sum += __shfl_xor(sum, 4); sum += __shfl_xor(sum, 8);
    float inv = 1.0f / sum;
    #pragma unroll
    for (int n = 0; n < 16; ++n)
      probs[rb + n * 16] = f2bf(acc[n][r] * inv);
  }
}

// ---------------------------------------------------------------------------
// PV: O[i][h*96+d] = probs[i][:] @ V[:][d].  Vt tile LDS, swizzle (row&7)<<4.
// ---------------------------------------------------------------------------
__global__ __launch_bounds__(256) void k_pv(
    const unsigned short* __restrict__ probs, const unsigned short* __restrict__ Vt,
    unsigned short* __restrict__ O)
{
  __shared__ __align__(16) unsigned short Vs[96 * 256];
  const int tid = threadIdx.x, l = tid & 63, w = tid >> 6;
  const int i0 = blockIdx.x * 64, bh = blockIdx.y, b = bh >> 3, h = bh & 7;
  const unsigned short* Vb = Vt + (size_t)bh * 96 * 256;
  #pragma unroll
  for (int i = 0; i < 12; ++i) {
    int o = i * 4096 + tid * 16;
    int row = o >> 9, c = o & 511;
    short8v v = *(const short8v*)(Vb + row * 256 + (c >> 1));
    *(short8v*)&Vs[row * 256 + ((c ^ ((row & 7) << 4)) >> 1)] = v;
  }
  short8v pa[8];
  const size_t prow = ((size_t)bh * 256 + i0 + w * 16 + (l & 15)) * 256;
  #pragma unroll
  for (int ks = 0; ks < 8; ++ks)
    pa[ks] = *(const short8v*)(probs + prow + ks * 32 + ((l >> 4) << 3));
  __syncthreads();

  f32x4 acc[6];
  #pragma unroll
  for (int n = 0; n < 6; ++n) {
    acc[n] = zero4();
    int rv = n * 16 + (l & 15);
    int swz = (rv & 7) << 4;
    #pragma unroll
    for (int ks = 0; ks < 8; ++ks) {
      short8v bq = *(const short8v*)&Vs[rv * 256 + (((ks * 64 + ((l >> 4) << 4)) ^ swz) >> 1)];
      acc[n] = __builtin_amdgcn_mfma_f32_16x16x32_bf16(pa[ks], bq, acc[n], 0, 0, 0);
    }
  }
  unsigned short* Ob = O + ((size_t)b * 256 + i0 + w * 16 + ((l >> 4) << 2)) * 768 + h * 96 + (l & 15);
  #pragma unroll
  for (int n = 0; n < 6; ++n)
    #pragma unroll
    for (int r = 0; r < 4; ++r)
      Ob[(size_t)r * 768 + n * 16] = f2bf(acc[n][r]);
}

// ---------------------------------------------------------------------------
// Final LN (row 0 of each batch) + classifier head -> out (8,2), fp32
// ---------------------------------------------------------------------------
__global__ __launch_bounds__(256) void k_cls(
    const float* __restrict__ x, const float* __restrict__ fg,
    const float* __restrict__ fb, const float* __restrict__ w1,
    const float* __restrict__ b1, const float* __restrict__ w2,
    const float* __restrict__ b2, float* __restrict__ out)
{
  __shared__ float ln[768];
  __shared__ float t1[768];
  __shared__ float red[8];
  __shared__ float r2[8];
  const int t = threadIdx.x;
  const int b = blockIdx.x;
  const float* xr = x + (size_t)b * 256 * 768;
  float v0 = xr[t], v1 = xr[t + 256], v2 = xr[t + 512];
  float s = v0 + v1 + v2;
  #pragma unroll
  for (int o = 32; o; o >>= 1) s += __shfl_down(s, o);
  if ((t & 63) == 0) red[t >> 6] = s;
  __syncthreads();
  float mean = (red[0] + red[1] + red[2] + red[3]) * (1.0f / 768.0f);
  float d0 = v0 - mean, d1 = v1 - mean, d2 = v2 - mean;
  float q = d0 * d0 + d1 * d1 + d2 * d2;
  #pragma unroll
  for (int o = 32; o; o >>= 1) q += __shfl_down(q, o);
  if ((t & 63) == 0) red[4 + (t >> 6)] = q;
  __syncthreads();
  float rstd = rsqrtf((red[4] + red[5] + red[6] + red[7]) * (1.0f / 768.0f) + 1e-3f);
  ln[t]       = d0 * rstd * fg[t]       + fb[t];
  ln[t + 256] = d1 * rstd * fg[t + 256] + fb[t + 256];
  ln[t + 512] = d2 * rstd * fg[t + 512] + fb[t + 512];
  __syncthreads();
  float a0 = b1[t], a1 = b1[t + 256], a2 = b1[t + 512];
  for (int d = 0; d < 768; ++d) {
    float lv = ln[d];
    a0 = fmaf(lv, w1[d * 768 + t], a0);
    a1 = fmaf(lv, w1[d * 768 + t + 256], a1);
    a2 = fmaf(lv, w1[d * 768 + t + 512], a2);
  }
  t1[t]       = gelu_f(a0);
  t1[t + 256] = gelu_f(a1);
  t1[t + 512] = gelu_f(a2);
  __syncthreads();
  float p0 = 0.f, p1 = 0.f;
  #pragma unroll
  for (int oo = 0; oo < 3; ++oo) {
    int d = t + oo * 256;
    p0 = fmaf(t1[d], w2[d * 2], p0);
    p1 = fmaf(t1[d], w2[d * 2 + 1], p1);
  }
  #pragma unroll
  for (int o = 32; o; o >>= 1) {
    p0 += __shfl_down(p0, o);
    p1 += __shfl_down(p1, o);
  }
  if ((t & 63) == 0) { r2[t >> 6] = p0; r2[4 + (t >> 6)] = p1; }
  __syncthreads();
  if (t == 0) {
    out[b * 2]     = r2[0] + r2[1] + r2[2] + r2[3] + b2[0];
    out[b * 2 + 1] = r2[4] + r2[5] + r2[6] + r2[7] + b2[1];
  }
}

// ---------------------------------------------------------------------------
extern "C" void kernel_launch(void* const* d_in, const int* in_sizes, int n_in,
                              void* d_out, int out_size, void* d_ws, size_t ws_size,
                              hipStream_t stream)
{
  const float* dist    = (const float*)d_in[0];
  const float* tok_emb = (const float*)d_in[1];
  const float* gmeans  = (const float*)d_in[2];
  const float* gstds   = (const float*)d_in[3];
  const float* gmul    = (const float*)d_in[4];
  const float* gbias   = (const float*)d_in[5];
  const float* gp1w    = (const float*)d_in[6];
  const float* gp1b    = (const float*)d_in[7];
  const float* gp2w    = (const float*)d_in[8];
  const float* gp2b    = (const float*)d_in[9];
  const float* embg    = (const float*)d_in[10];
  const float* embb    = (const float*)d_in[11];
  const float* Wq      = (const float*)d_in[12];
  const float* bq      = (const float*)d_in[13];
  const float* Wo      = (const float*)d_in[14];
  const float* bo      = (const float*)d_in[15];
  const float* ln1g    = (const float*)d_in[16];
  const float* ln1b    = (const float*)d_in[17];
  const float* W1      = (const float*)d_in[18];
  const float* b1      = (const float*)d_in[19];
  const float* W2      = (const float*)d_in[20];
  const float* b2      = (const float*)d_in[21];
  const float* ln2g    = (const float*)d_in[22];
  const float* ln2b    = (const float*)d_in[23];
  const float* fing    = (const float*)d_in[24];
  const float* finb    = (const float*)d_in[25];
  const float* cw1     = (const float*)d_in[26];
  const float* cb1     = (const float*)d_in[27];
  const float* cw2     = (const float*)d_in[28];
  const float* cb2     = (const float*)d_in[29];
  const int*   tokens  = (const int*)d_in[30];
  const int*   edge    = (const int*)d_in[31];

  // workspace layout
  float* ws   = (float*)d_ws;
  float* bias = ws;                       // 4,194,304 f32
  float* x    = bias + 4194304;           // 1,572,864 f32
  unsigned short* hO    = (unsigned short*)(x + 1572864);  // 1,572,864 bf16 (h & O alias)
  unsigned short* P     = hO + 1572864;                    // 1,572,864 bf16
  unsigned short* big   = P + 1572864;                     // 6,291,456 bf16 (f1 | probs+Vt)
  unsigned short* probs = big;                             // 4,194,304 bf16
  unsigned short* Vt    = big + 4194304;                   // 1,572,864 bf16
  unsigned short* f1    = big;                             // 6,291,456 bf16
  unsigned short* Wqt   = big + 6291456;                   // 4,718,592 bf16
  unsigned short* Wot   = Wqt + 4718592;                   // 4,718,592 bf16
  unsigned short* W1t   = Wot + 4718592;                   // 18,874,368 bf16
  unsigned short* W2t   = W1t + 18874368;                  // 18,874,368 bf16
  unsigned short* g1t   = W2t + 18874368;                  // 16,384 bf16
  // total ~136.4 MiB

  k_cast_t<<<dim3(12, 12, 8), 256, 0, stream>>>(Wq, Wqt, 768, 768);
  k_cast_t<<<dim3(12, 12, 8), 256, 0, stream>>>(Wo, Wot, 768, 768);
  k_cast_t<<<dim3(12, 48, 8), 256, 0, stream>>>(W1, W1t, 768, 3072);
  k_cast_t<<<dim3(48, 12, 8), 256, 0, stream>>>(W2, W2t, 3072, 768);
  k_cast_t<<<dim3(2, 2, 1), 256, 0, stream>>>(gp1w, g1t, 128, 128);

  k_gauss<<<8192, 256, 0, stream>>>(dist, edge, gmul, gbias, gmeans, gstds,
                                    g1t, gp1b, gp2w, gp2b, bias);
  k_embed_ln<<<2048, 256, 0, stream>>>(tok_emb, tokens, embg, embb, x);

  for (int l = 0; l < 8; ++l) {
    k_ln_bf<<<2048, 256, 0, stream>>>(x, ln1g + l * 768, ln1b + l * 768, hO);
    k_gemm<64, 0><<<dim3(16, 12), 256, 0, stream>>>(
        hO, Wqt + (size_t)l * 589824, bq + l * 768, nullptr, P, 768, 768);
    k_transV<<<dim3(4, 64), 256, 0, stream>>>(P, Vt);
    k_scores_sm<<<dim3(4, 64), 256, 0, stream>>>(P, bias, probs);
    k_pv<<<dim3(4, 64), 256, 0, stream>>>(probs, Vt, hO);
    k_gemm<64, 2><<<dim3(16, 12), 256, 0, stream>>>(
        hO, Wot + (size_t)l * 589824, bo + l * 768, x, x, 768, 768);
    k_ln_bf<<<2048, 256, 0, stream>>>(x, ln2g + l * 768, ln2b + l * 768, hO);
    k_gemm<128, 1><<<dim3(16, 24), 256, 0, stream>>>(
        hO, W1t + (size_t)l * 2359296, b1 + l * 3072, nullptr, f1, 3072, 768);
    k_gemm<64, 2><<<dim3(16, 12), 256, 0, stream>>>(
        f1, W2t + (size_t)l * 2359296, b2 + l * 768, x, x, 768, 3072);
  }
  k_cls<<<8, 256, 0, stream>>>(x, fing, finb, cw1, cb1, cw2, cb2, (float*)d_out);
}